// Round 1
// baseline (664.037 us; speedup 1.0000x reference)
//
#include <hip/hip_runtime.h>
#include <hip/hip_bf16.h>

#define KBOX 1024
#define KM1  1023
#define NROWS (KBOX * KM1)        // 1047552 off-diagonal pairs
#define BM   32                   // pairs per block
#define HD   128                  // hidden dim / output dim
#define LDH  136                  // padded LDS row stride (bf16 elems): 272B rows -> <=2-way b128 conflicts
#define THREADS 256
#define NBLOCK (NROWS / BM)       // 32736 exactly

typedef __attribute__((ext_vector_type(8))) short bf16x8;   // 8 bf16 = 4 VGPRs (MFMA A/B frag)
typedef __attribute__((ext_vector_type(4))) float floatx4;  // MFMA C/D frag

// One-time repack: W2 (128x128 fp32, row-major [k][n]) -> bf16 transposed [n][k] in workspace.
// Makes the per-block LDS staging coalesced and conflict-free.
__global__ void prep_w2(const float* __restrict__ W2, __hip_bfloat16* __restrict__ w2t) {
    int idx = blockIdx.x * blockDim.x + threadIdx.x;   // 0..16383
    int n = idx >> 7;
    int k = idx & 127;
    w2t[n * HD + k] = __float2bfloat16(W2[k * HD + n]);
}

__global__ __launch_bounds__(THREADS, 3)
void pair_mlp(const float* __restrict__ boxes,
              const float* __restrict__ W1,
              const float* __restrict__ b1,
              const __hip_bfloat16* __restrict__ w2t,
              const float* __restrict__ b2,
              float* __restrict__ out) {
    // LDS: 34816 + 8704 + 8704 + 2048 = 54272 B -> 3 blocks/CU (3*54272 = 162816 <= 163840)
    __shared__ __align__(16) __hip_bfloat16 sW2[HD * LDH];   // [n][k] bf16, stride 136
    __shared__ __align__(16) __hip_bfloat16 sHhi[BM * LDH];  // [pair][k] bf16 hi
    __shared__ __align__(16) __hip_bfloat16 sHlo[BM * LDH];  // [pair][k] bf16 lo
    __shared__ __align__(16) float sFeat[BM * 16];           // 13 feats padded to 16

    const int tid = threadIdx.x;
    const int p0  = blockIdx.x * BM;

    // ---- stage transposed bf16 W2 into padded LDS (coalesced b128 in/out) ----
    #pragma unroll
    for (int it = 0; it < 8; ++it) {
        int c  = tid + it * THREADS;   // chunk 0..2047, 8 bf16 each
        int n  = c >> 4;
        int kc = c & 15;
        bf16x8 v = *(const bf16x8*)(w2t + n * HD + kc * 8);
        *(bf16x8*)(&sW2[n * LDH + kc * 8]) = v;
    }

    // ---- per-pair 13 features (threads 0..31, one pair each) ----
    if (tid < BM) {
        unsigned r   = (unsigned)(p0 + tid);
        unsigned i   = r / KM1;                  // magic-mul const division
        unsigned rem = r - i * KM1;
        unsigned j   = rem + (rem >= i ? 1u : 0u);
        float4 bi = *(const float4*)(boxes + 4u * i);
        float4 bj = *(const float4*)(boxes + 4u * j);
        float xi = bi.x, yi = bi.y, wi = bi.z, hi = bi.w;
        float xj = bj.x, yj = bj.y, wj = bj.z, hj = bj.w;
        float dx = (xj - xi) / wi;
        float dy = (yj - yi) / hi;
        float dw = logf(wj / wi + 1e-6f);
        float dh = logf(hj / hi + 1e-6f);
        float iw = fmaxf(0.0f, fminf(xi + wi, xj + wj) - fmaxf(xi, xj));
        float ih = fmaxf(0.0f, fminf(yi + hi, yj + hj) - fmaxf(yi, yj));
        float inter = iw * ih;
        float uni   = wi * hi + wj * hj - inter;
        float iou   = inter / (uni + 1e-6f);
        float f[13] = {dx, dy, dw, dh, wi, hi, wj, hj, iou, xi, yi, xj, yj};
        #pragma unroll
        for (int t = 0; t < 13; ++t) sFeat[tid * 16 + t] = f[t];
    }

    // ---- layer 1 in fp32: W1 column in registers, reused across 16 pairs ----
    const int c     = tid & 127;   // hidden index
    const int phalf = tid >> 7;    // 0/1: even/odd pairs
    float w1c[13];
    #pragma unroll
    for (int f = 0; f < 13; ++f) w1c[f] = W1[f * HD + c];
    const float b1c = b1[c];

    __syncthreads();   // feats + W2 staged

    #pragma unroll
    for (int pi = 0; pi < 16; ++pi) {
        int p = phalf + pi * 2;
        const float4* fp = (const float4*)(&sFeat[p * 16]);   // broadcast reads
        float4 f0 = fp[0], f1 = fp[1], f2 = fp[2];
        float f12 = sFeat[p * 16 + 12];
        float ff[13] = {f0.x, f0.y, f0.z, f0.w, f1.x, f1.y, f1.z, f1.w,
                        f2.x, f2.y, f2.z, f2.w, f12};
        float h = b1c;
        #pragma unroll
        for (int f = 0; f < 13; ++f) h = fmaf(ff[f], w1c[f], h);
        h = fmaxf(h, 0.0f);
        __hip_bfloat16 hh = __float2bfloat16(h);
        float hr = h - __bfloat162float(hh);
        __hip_bfloat16 hl = __float2bfloat16(hr);
        sHhi[p * LDH + c] = hh;
        sHlo[p * LDH + c] = hl;
    }

    __syncthreads();   // h tile ready

    // ---- layer 2: MFMA 16x16x32 bf16, 2-term split (h_hi + h_lo) @ bf16(W2) ----
    const int lane  = tid & 63;
    const int wave  = tid >> 6;     // 0..3
    const int waveM = wave & 1;     // 16-pair half
    const int waveN = wave >> 1;    // 64-col half
    const int lr    = lane & 15;    // A row / B col / C col
    const int quad  = lane >> 4;    // k sub-block; C row group

    floatx4 acc[4] = {{0.f,0.f,0.f,0.f},{0.f,0.f,0.f,0.f},
                      {0.f,0.f,0.f,0.f},{0.f,0.f,0.f,0.f}};

    const int arow = waveM * 16 + lr;           // pair within block
    #pragma unroll
    for (int ks = 0; ks < 4; ++ks) {
        int kb = ks * 32 + quad * 8;            // k = quad*8+j within the K=32 step
        bf16x8 ahi = *(const bf16x8*)(&sHhi[arow * LDH + kb]);
        bf16x8 alo = *(const bf16x8*)(&sHlo[arow * LDH + kb]);
        #pragma unroll
        for (int nt = 0; nt < 4; ++nt) {
            int ncol = waveN * 64 + nt * 16 + lr;
            bf16x8 b = *(const bf16x8*)(&sW2[ncol * LDH + kb]);
            acc[nt] = __builtin_amdgcn_mfma_f32_16x16x32_bf16(ahi, b, acc[nt], 0, 0, 0);
            acc[nt] = __builtin_amdgcn_mfma_f32_16x16x32_bf16(alo, b, acc[nt], 0, 0, 0);
        }
    }

    // ---- epilogue: +b2, fp32 store (C/D: col=lane&15, row=quad*4+reg) ----
    #pragma unroll
    for (int nt = 0; nt < 4; ++nt) {
        int ncol   = waveN * 64 + nt * 16 + lr;
        float bias = b2[ncol];
        #pragma unroll
        for (int reg = 0; reg < 4; ++reg) {
            int prow = waveM * 16 + quad * 4 + reg;
            out[(size_t)(p0 + prow) * HD + ncol] = acc[nt][reg] + bias;
        }
    }
}

extern "C" void kernel_launch(void* const* d_in, const int* in_sizes, int n_in,
                              void* d_out, int out_size, void* d_ws, size_t ws_size,
                              hipStream_t stream) {
    (void)in_sizes; (void)n_in; (void)out_size; (void)ws_size;
    const float* boxes = (const float*)d_in[0];
    const float* W1    = (const float*)d_in[1];
    const float* b1    = (const float*)d_in[2];
    const float* W2    = (const float*)d_in[3];
    const float* b2    = (const float*)d_in[4];
    float* out = (float*)d_out;
    __hip_bfloat16* w2t = (__hip_bfloat16*)d_ws;   // 32 KB scratch

    prep_w2<<<64, 256, 0, stream>>>(W2, w2t);
    pair_mlp<<<NBLOCK, THREADS, 0, stream>>>(boxes, W1, b1, w2t, b2, out);
}